// Round 4
// baseline (794.121 us; speedup 1.0000x reference)
//
#include <hip/hip_runtime.h>
#include <hip/hip_bf16.h>
#include <stdint.h>

#define HIDDEN 4096
#define RANK   8
#define SCALING 2.0f
#define EPS    1e-8f
#define SEQ    2048
#define BATCH  2
#define NH     32
#define NKVH   8
#define HD     128
#define MROWS  (BATCH*SEQ)   // 4096
#define NQKV   6144          // 4096 q | 1024 k | 1024 v

typedef __attribute__((ext_vector_type(8))) short bf16x8;
typedef __attribute__((ext_vector_type(4))) short bf16x4;
typedef __attribute__((ext_vector_type(4))) float f32x4;

__device__ __forceinline__ void gload_lds16(const void* g, void* lds) {
  __builtin_amdgcn_global_load_lds((__attribute__((address_space(1))) void*)g,
                                   (__attribute__((address_space(3))) void*)lds,
                                   16, 0, 0);
}

__device__ __forceinline__ unsigned short f2bf(float f) {
  __hip_bfloat16 h = __float2bfloat16(f);
  return *reinterpret_cast<unsigned short*>(&h);
}

__device__ __forceinline__ void store_c(float* p, float v) { *p = v; }
__device__ __forceinline__ void store_c(__hip_bfloat16* p, float v) { *p = __float2bfloat16(v); }

__device__ __forceinline__ bf16x8 lds_read8_b64(const short* p) {
  bf16x4 lo = *(const bf16x4*)p;
  bf16x4 hi = *(const bf16x4*)(p + 4);
  bf16x8 r;
  r[0]=lo[0]; r[1]=lo[1]; r[2]=lo[2]; r[3]=lo[3];
  r[4]=hi[0]; r[5]=hi[1]; r[6]=hi[2]; r[7]=hi[3];
  return r;
}

// ---------------- DoRA W_d row (device helper) ----------------
__device__ __forceinline__ void wd_row(const float* __restrict__ W, const float* __restrict__ A,
                                       const float* __restrict__ B, const float* __restrict__ m,
                                       unsigned short* __restrict__ out, int row, int tid,
                                       float* wsum) {
  float bl[RANK];
#pragma unroll
  for (int t = 0; t < RANK; ++t) bl[t] = SCALING * B[row*RANK + t];
  float ev[16];
  float ss = 0.f;
#pragma unroll
  for (int it = 0; it < 4; ++it) {
    const int j = it*1024 + tid*4;
    const float4 wv = *(const float4*)&W[(size_t)row*HIDDEN + j];
    float e0 = wv.x, e1 = wv.y, e2 = wv.z, e3 = wv.w;
#pragma unroll
    for (int t = 0; t < RANK; ++t) {
      const float4 av = *(const float4*)&A[t*HIDDEN + j];
      e0 += bl[t]*av.x; e1 += bl[t]*av.y; e2 += bl[t]*av.z; e3 += bl[t]*av.w;
    }
    ev[it*4+0]=e0; ev[it*4+1]=e1; ev[it*4+2]=e2; ev[it*4+3]=e3;
    ss += e0*e0 + e1*e1 + e2*e2 + e3*e3;
  }
#pragma unroll
  for (int off = 32; off > 0; off >>= 1) ss += __shfl_down(ss, off, 64);
  if ((tid & 63) == 0) wsum[tid >> 6] = ss;
  __syncthreads();
  const float norm = sqrtf(wsum[0]+wsum[1]+wsum[2]+wsum[3]);
  const float scl = m[row] / (norm + EPS);
#pragma unroll
  for (int it = 0; it < 4; ++it) {
    const int j = it*1024 + tid*4;
    ushort4 pk;
    pk.x = f2bf(ev[it*4+0]*scl); pk.y = f2bf(ev[it*4+1]*scl);
    pk.z = f2bf(ev[it*4+2]*scl); pk.w = f2bf(ev[it*4+3]*scl);
    *(ushort4*)&out[(size_t)row*HIDDEN + j] = pk;
  }
}

// ---------------- prep: cast x -> bf16 + all DoRA W_d in one launch ----------------
__launch_bounds__(256)
__global__ void prep_kernel(const float* __restrict__ x, unsigned short* __restrict__ xbf,
                            const float* Wq, const float* Aq, const float* Bq, const float* mq, unsigned short* wdq,
                            const float* Wk, const float* Ak, const float* Bk, const float* mk, unsigned short* wdk,
                            const float* Wv, const float* Av, const float* Bv, const float* mv, unsigned short* wdv,
                            const float* Wo, const float* Ao, const float* Bo, const float* mo, unsigned short* wdo) {
  __shared__ float wsum[4];
  const int bid = blockIdx.x;
  const int tid = threadIdx.x;
  if (bid < 16384) {
    const size_t i = ((size_t)bid * 256 + tid) * 4;
    const float4 v = *(const float4*)&x[i];
    ushort4 pk;
    pk.x = f2bf(v.x); pk.y = f2bf(v.y); pk.z = f2bf(v.z); pk.w = f2bf(v.w);
    *(ushort4*)&xbf[i] = pk;
  } else if (bid < 20480) {
    wd_row(Wq, Aq, Bq, mq, wdq, bid - 16384, tid, wsum);
  } else if (bid < 21504) {
    wd_row(Wk, Ak, Bk, mk, wdk, bid - 20480, tid, wsum);
  } else if (bid < 22528) {
    wd_row(Wv, Av, Bv, mv, wdv, bid - 21504, tid, wsum);
  } else {
    wd_row(Wo, Ao, Bo, mo, wdo, bid - 22528, tid, wsum);
  }
}

__launch_bounds__(256)
__global__ void wd_kernel(const float* __restrict__ W, const float* __restrict__ A,
                          const float* __restrict__ B, const float* __restrict__ m,
                          unsigned short* __restrict__ out) {
  __shared__ float wsum[4];
  wd_row(W, A, B, m, out, blockIdx.x, threadIdx.x, wsum);
}

// ---------------- 256-row pipelined bf16 GEMM: C[M,N] = A[M,K] * B[N,K]^T ----------------
// Tile = 256 x (NREP*64); NREP=3 QKV (grid 512 = 2 rounds), NREP=4 O-proj (grid 256).
// Round 4: MERGED sections — 2 sections per K-tile (section = one K-half x all 8 M-frags
// x NREP), ONE barrier per section (128 barriers/block vs 256). Per section:
//   [MFMA 8xNREP (setprio)] [reads for s+1: 8 af + NREP bfr, single-buffered regs]
//   [stage units 2s+6, 2s+7] [vmcnt(4)] [BAR]
// Unit u covers region (parity=(u>>2)&1, j=u&3): j0=A-kh0, j1=B-kh0, j2=A-kh1, j3=B-kh1.
// Section s (tile s>>1, ks s&1) MFMA-consumes units 2s,2s+1 (prefetched in section s-1).
// Hazards:
//  - RAW: end of section s-1 has units <= 2(s-1)+7 issued; vmcnt(4) => units <= 2s+3
//    landed; section-s reads need units 2s+2,2s+3. Prologue: 6 units + vmcnt(4) =>
//    units 0..3 landed, covering prologue reads (0,1) and section-0 reads (2,3).
//  - WAR: region of units 2s+2,2s+3 (read in section s, lgkm-drained before MFMA in
//    section s+1) is rewritten by units 2s+8,2s+9 issued in section s+1 AFTER the
//    barrier ending section s... (actually units 2s+8,9 = same-parity different-j;
//    same-region rewrite is units 2s+10,11, issued section s+2 — 2 barriers after the
//    last read's drain).
// Accumulation order per acc element unchanged (tiles asc, ks0 then ks1) => numerics
// identical to rounds 1-3.
__device__ __forceinline__ void stage_u(const __hip_bfloat16* __restrict__ Ab,
                                        const __hip_bfloat16* __restrict__ Bb,
                                        const int K, __hip_bfloat16* sbuf,
                                        const int par, const int tau, const int j,
                                        const int w, const int l, const int kchunk) {
  const __hip_bfloat16* src = (j & 1) ? Bb : Ab;
  __hip_bfloat16* dst = sbuf + (par << 15) + (j << 13);
  const int k0 = (tau << 6) + ((j >> 1) << 5) + (kchunk << 3);
  const int r0 = (w << 4) + (l >> 2);
  gload_lds16(src + (size_t)r0 * K + k0, dst + (w << 9));
  gload_lds16(src + (size_t)(r0 + 128) * K + k0, dst + 4096 + (w << 9));
}

template<typename CT, int NREP>
__launch_bounds__(512, 2)
__global__ void gemm256(const __hip_bfloat16* __restrict__ A,
                        const __hip_bfloat16* __restrict__ B,
                        CT* __restrict__ C, const int M, const int N, const int K) {
  (void)M;
  __shared__ __hip_bfloat16 sb[65536];
  const int tid = threadIdx.x;
  const int w = tid >> 6, l = tid & 63;
  const int wr = w >> 2, wc = w & 3;           // 2x4 wave grid; wave tile 128 x NREP*16
  const int q4 = l >> 4, ln = l & 15;
  const int nbn = N / (NREP * 64);
  const int cpx = gridDim.x >> 3;              // grid % 8 == 0 at both call sites
  const int fid = (blockIdx.x & 7) * cpx + (blockIdx.x >> 3);
  const int tM = (fid / nbn) << 8;
  const int tN = (fid % nbn) * (NREP * 64);
  const int NT = K >> 6;                       // 64, even
  const __hip_bfloat16* Ab = A + (size_t)tM * K;
  const __hip_bfloat16* Bb = B + (size_t)tN * K;
  // write-side pre-swizzle: thread covers slot (row=tid>>2, c=tid&3); f(row)=(tid>>3)&3
  const int kchunk = (l & 3) ^ ((l >> 3) & 3);
  // read-side: frag rows == ln (mod 16) -> f(row)=(ln>>1)&3, per-lane constant
  const int slotoff = (q4 ^ ((ln >> 1) & 3)) << 3;

  f32x4 acc[8][NREP] = {};
  bf16x8 af[8];                                // single-buffered: reads for s+1 issue
  bf16x8 bfr[NREP];                            // after MFMA s (same regs, WAR via HW/alloc)
  const short* sp = (const short*)sb;
  const int arow0 = wr * 128 + ln;
  const int brow0 = wc * (NREP * 16) + ln;

  // prologue: units 0..5 = (t0,U0..U3),(t1,U0,U1); vmcnt(4) => units 0..3 landed.
#pragma unroll
  for (int s = 0; s < 6; ++s)
    stage_u(Ab, Bb, K, sb, (s >> 2) & 1, s >> 2, s & 3, w, l, kchunk);
  asm volatile("s_waitcnt vmcnt(4)" ::: "memory");
  __builtin_amdgcn_s_barrier();
  // reads for section 0 (tile0, ks0, parity0)
#pragma unroll
  for (int i = 0; i < 8; ++i)
    af[i] = *(const bf16x8*)&sp[(arow0 + i*16) * 32 + slotoff];
#pragma unroll
  for (int i = 0; i < NREP; ++i)
    bfr[i] = *(const bf16x8*)&sp[8192 + (brow0 + i*16) * 32 + slotoff];

  // stage-unit schedule per pp (tt even => all compile-time):
  //   pp0: tiles tt+1 j2,j3 (par 1) | pp1: tt+2 j0,j1 (par 0)
  //   pp2: tt+2 j2,j3 (par 0)       | pp3: tt+3 j0,j1 (par 1)
  const int stg_dt[4] = {1, 2, 2, 3};
  const int stg_j0[4] = {2, 0, 2, 0};
  const int stg_par[4] = {1, 0, 0, 1};

  for (int tt = 0; tt < NT; tt += 2) {
#pragma unroll
    for (int pp = 0; pp < 4; ++pp) {           // section s = 2*tt + pp
      // ---- MFMA section s: frags prefetched one section ago ----
      __builtin_amdgcn_s_setprio(1);
#pragma unroll
      for (int i = 0; i < 8; ++i)
#pragma unroll
        for (int ni = 0; ni < NREP; ++ni)
          acc[i][ni] = __builtin_amdgcn_mfma_f32_16x16x32_bf16(af[i], bfr[ni], acc[i][ni], 0, 0, 0);
      __builtin_amdgcn_s_setprio(0);
      // ---- reads for section s+1 (parity/ks compile-time; last-section reads are
      //      dead (stale LDS) and never consumed — harmless) ----
      {
        const int nb  = (((pp + 1) >> 1) & 1) << 15;
        const int nks = (pp + 1) & 1;
#pragma unroll
        for (int i = 0; i < 8; ++i)
          af[i] = *(const bf16x8*)&sp[nb + (nks << 14) + (arow0 + i*16) * 32 + slotoff];
#pragma unroll
        for (int i = 0; i < NREP; ++i)
          bfr[i] = *(const bf16x8*)&sp[nb + 8192 + (nks << 14) + (brow0 + i*16) * 32 + slotoff];
      }
      // ---- stage units 2s+6, 2s+7 ----
      {
        const int st = tt + stg_dt[pp];
        if (st < NT) {
          stage_u(Ab, Bb, K, sb, stg_par[pp], st, stg_j0[pp], w, l, kchunk);
          stage_u(Ab, Bb, K, sb, stg_par[pp], st, stg_j0[pp] + 1, w, l, kchunk);
        }
      }
      asm volatile("s_waitcnt vmcnt(4)" ::: "memory");
      __builtin_amdgcn_s_barrier();
    }
  }

  const int r0 = tM + wr * 128 + q4 * 4;
  const int c0 = tN + wc * (NREP * 16) + ln;
#pragma unroll
  for (int mi = 0; mi < 8; ++mi)
#pragma unroll
    for (int ni = 0; ni < NREP; ++ni)
#pragma unroll
      for (int r = 0; r < 4; ++r)
        store_c(&C[(size_t)(r0 + mi * 16 + r) * N + c0 + ni * 16], acc[mi][ni][r]);
}

// ---------------- flash attention v2 (causal, GQA) ----------------
#define VT_S 68
#define PS_S 68
__launch_bounds__(256, 3)
__global__ void attn_kernel(const __hip_bfloat16* __restrict__ qkv,
                            __hip_bfloat16* __restrict__ out) {
  const int bid = blockIdx.x;
  const int qt = 15 - (bid >> 6);      // big tiles first
  const int hb = bid & 63;
  const int h  = hb & 31;
  const int b  = hb >> 5;
  const int kvh = h >> 2;
  const int tid = threadIdx.x;
  const int w = tid >> 6, l = tid & 63;
  const int q4 = l >> 4;
  const int ln = l & 15;
  const int sw = ln & 7;

  __shared__ __hip_bfloat16 Ks[64*128];
  __shared__ __hip_bfloat16 Vt[128*VT_S];
  __shared__ __hip_bfloat16 Ps[4][2][16*PS_S];

  const __hip_bfloat16* kb = qkv + (size_t)(b*SEQ)*NQKV + HIDDEN + kvh*HD;
  const __hip_bfloat16* vb = qkv + (size_t)(b*SEQ)*NQKV + (HIDDEN+1024) + kvh*HD;

  const int Q0 = qt*128;

  const int krow = l >> 4;
  const int kchunk = ((l & 15) ^ krow ^ ((w & 1) << 2)) * 8;

  const int vc4 = (tid & 15) * 4;
  const int vd0 = (tid >> 4) * 8;

  bf16x8 aq[2][4];
#pragma unroll
  for (int hf = 0; hf < 2; ++hf) {
    const __hip_bfloat16* qr = qkv + (size_t)(b*SEQ + Q0 + hf*64 + w*16 + ln)*NQKV + h*HD;
#pragma unroll
    for (int ks = 0; ks < 4; ++ks) {
      uint4 raw = *(const uint4*)(qr + ks*32 + q4*8);
      aq[hf][ks] = *(const bf16x8*)&raw;
    }
  }

  f32x4 o[2][8] = {};
  float mx[2] = {-1e30f, -1e30f};
  float lsum[2] = {0.f, 0.f};
  const float sc = 0.08838834764831845f;  // 1/sqrt(128)
  const int qabs0 = Q0 + w*16 + ln;

  const int jmax = 2*qt + 1;
  for (int j = 0; j <= jmax; ++j) {
    const int do0 = (j <= 2*qt);
    __syncthreads();
#pragma unroll
    for (int i = 0; i < 4; ++i) {
      const int rr = i*16 + w*4;
      gload_lds16(kb + (size_t)(j*64 + rr + krow)*NQKV + kchunk, &Ks[rr*128]);
    }
    {
      uint4 r0 = *(const uint4*)(vb + (size_t)(j*64 + vc4 + 0)*NQKV + vd0);
      uint4 r1 = *(const uint4*)(vb + (size_t)(j*64 + vc4 + 1)*NQKV + vd0);
      uint4 r2 = *(const uint4*)(vb + (size_t)(j*64 + vc4 + 2)*NQKV + vd0);
      uint4 r3 = *(const uint4*)(vb + (size_t)(j*64 + vc4 + 3)*NQKV + vd0);
      const unsigned short* p0 = (const unsigned short*)&r0;
      const unsigned short* p1 = (const unsigned short*)&r1;
      const unsigned short* p2 = (const unsigned short*)&r2;
      const unsigned short* p3 = (const unsigned short*)&r3;
#pragma unroll
      for (int t = 0; t < 8; ++t) {
        ushort4 pk; pk.x = p0[t]; pk.y = p1[t]; pk.z = p2[t]; pk.w = p3[t];
        *(ushort4*)&Vt[(vd0 + t)*VT_S + vc4] = pk;
      }
    }
    __syncthreads();

    f32x4 s[2][4] = {};
    const short* Kp = (const short*)Ks;
#pragma unroll
    for (int ks = 0; ks < 4; ++ks) {
      const int slot = ((ks*4 + q4) ^ sw) * 8;
#pragma unroll
      for (int nt = 0; nt < 4; ++nt) {
        bf16x8 bk = *(const bf16x8*)&Kp[(nt*16 + ln)*128 + slot];
        if (do0) s[0][nt] = __builtin_amdgcn_mfma_f32_16x16x32_bf16(bk, aq[0][ks], s[0][nt], 0, 0, 0);
        s[1][nt] = __builtin_amdgcn_mfma_f32_16x16x32_bf16(bk, aq[1][ks], s[1][nt], 0, 0, 0);
      }
    }

#pragma unroll
    for (int hf = 0; hf < 2; ++hf) {
      if (hf == 0 && !do0) continue;
      const int qabs = qabs0 + hf*64;
      if (j == 2*qt + hf) {
#pragma unroll
        for (int nt = 0; nt < 4; ++nt)
#pragma unroll
          for (int r = 0; r < 4; ++r) {
            const int kvabs = j*64 + nt*16 + q4*4 + r;
            if (kvabs > qabs) s[hf][nt][r] = -1e30f;
          }
      }
      float vmax = mx[hf];
#pragma unroll
      for (int nt = 0; nt < 4; ++nt)
#pragma unroll
        for (int r = 0; r < 4; ++r) vmax = fmaxf(vmax, s[hf][nt][r]);
      vmax = fmaxf(vmax, __shfl_xor(vmax, 16, 64));
      vmax = fmaxf(vmax, __shfl_xor(vmax, 32, 64));
      const float alpha = __expf((mx[hf] - vmax) * sc);
      float rs = 0.f;
#pragma unroll
      for (int nt = 0; nt < 4; ++nt)
#pragma unroll
        for (int r = 0; r < 4; ++r) {
          const float e = __expf((s[hf][nt][r] - vmax) * sc);
          s[hf][nt][r] = e; rs += e;
        }
      rs += __shfl_xor(rs, 16, 64);
      rs += __shfl_xor(rs, 32, 64);
      mx[hf] = vmax;
      lsum[hf] = lsum[hf]*alpha + rs;
#pragma unroll
      for (int r = 0; r < 4; ++r) {
        const float ar = __shfl(alpha, q4*4 + r, 64);
#pragma unroll
        for (int ni = 0; ni < 8; ++ni) o[hf][ni][r] *= ar;
      }
      __hip_bfloat16* Pw = Ps[w][hf];
#pragma unroll
      for (int nt = 0; nt < 4; ++nt) {
        ushort4 pk;
        pk.x = f2bf(s[hf][nt][0]); pk.y = f2bf(s[hf][nt][1]);
        pk.z = f2bf(s[hf][nt][2]); pk.w = f2bf(s[hf][nt][3]);
        *(ushort4*)&Pw[ln*PS_S + nt*16 + q4*4] = pk;
      }
    }

    const short* Vp = (const short*)Vt;
    const short* Pp0 = (const short*)Ps[w][0];
    const short* Pp1 = (const short*)Ps[w][1];
#pragma unroll
    for (int ks = 0; ks < 2; ++ks) {
      bf16x8 ap0 = lds_read8_b64(&Pp0[ln*PS_S + ks*32 + q4*8]);
      bf16x8 ap1 = lds_read8_b64(&Pp1[ln*PS_S + ks*32 + q4*8]);
#pragma unroll
      for (int ni = 0; ni < 8; ++ni) {
        bf16x8 bv = lds_read8_b64(&Vp[(ni*16 + ln)*VT_S + ks*32 + q4*8]);
        if (do0) o[0][ni] = __builtin_amdgcn_mfma_f32_16x16x32_bf16(ap0, bv, o[0][ni], 0, 0, 0);
        o[1][ni] = __builtin_amdgcn_mfma_f32_16x16x32_bf16(ap1, bv, o[1][ni], 0, 0, 0);
      }
    }
  }

#pragma unroll
  for (int hf = 0; hf < 2; ++hf) {
    const int row0 = b*SEQ + Q0 + hf*64 + w*16 + q4*4;
#pragma unroll
    for (int r = 0; r < 4; ++r) {
      const float lr = __shfl(lsum[hf], q4*4 + r, 64);
      const float inv = 1.f / lr;
#pragma unroll
      for (int ni = 0; ni < 8; ++ni)
        out[(size_t)(row0 + r)*HIDDEN + h*HD + ni*16 + ln] = __float2bfloat16(o[hf][ni][r] * inv);
    }
  }
}

extern "C" void kernel_launch(void* const* d_in, const int* in_sizes, int n_in,
                              void* d_out, int out_size, void* d_ws, size_t ws_size,
                              hipStream_t stream) {
  (void)in_sizes; (void)n_in; (void)out_size;
  const float* x  = (const float*)d_in[0];
  const float* Wq = (const float*)d_in[2];
  const float* Aq = (const float*)d_in[3];
  const float* Bq = (const float*)d_in[4];
  const float* mq = (const float*)d_in[5];
  const float* Wk = (const float*)d_in[6];
  const float* Ak = (const float*)d_in[7];
  const float* Bk = (const float*)d_in[8];
  const float* mk = (const float*)d_in[9];
  const float* Wv = (const float*)d_in[10];
  const float* Av = (const float*)d_in[11];
  const float* Bv = (const float*)d_in[12];
  const float* mv = (const float*)d_in[13];
  const float* Wo = (const float*)d_in[14];
  const float* Ao = (const float*)d_in[15];
  const float* Bo = (const float*)d_in[16];
  const float* mo = (const float*)d_in[17];

  char* ws = (char*)d_ws;
  __hip_bfloat16* xbf = (__hip_bfloat16*)ws;                          // 32 MiB, reused as attn_out
  __hip_bfloat16* wd  = (__hip_bfloat16*)(ws + (size_t)33554432);     // 48 MiB
  __hip_bfloat16* qkv = (__hip_bfloat16*)(ws + (size_t)83886080);     // 48 MiB
  const bool big = ws_size >= (size_t)167772160;                      // 160 MiB
  __hip_bfloat16* wdo = big ? (__hip_bfloat16*)(ws + (size_t)134217728) : wd;

  prep_kernel<<<big ? 26624 : 22528, 256, 0, stream>>>(
      x, (unsigned short*)xbf,
      Wq, Aq, Bq, mq, (unsigned short*)wd,
      Wk, Ak, Bk, mk, (unsigned short*)(wd + (size_t)4096*4096),
      Wv, Av, Bv, mv, (unsigned short*)(wd + (size_t)5120*4096),
      Wo, Ao, Bo, mo, (unsigned short*)wdo);
  gemm256<__hip_bfloat16, 3><<<512, 512, 0, stream>>>(xbf, wd, qkv, MROWS, NQKV, HIDDEN);
  if (!big)
    wd_kernel<<<4096, 256, 0, stream>>>(Wo, Ao, Bo, mo, (unsigned short*)wdo);
  attn_kernel<<<1024, 256, 0, stream>>>(qkv, xbf);
  gemm256<float, 4><<<256, 512, 0, stream>>>(xbf, wdo, (float*)d_out, MROWS, HIDDEN, HIDDEN);
}

// Round 6
// 767.438 us; speedup vs baseline: 1.0348x; 1.0348x over previous
//
#include <hip/hip_runtime.h>
#include <hip/hip_bf16.h>
#include <stdint.h>

#define HIDDEN 4096
#define RANK   8
#define SCALING 2.0f
#define EPS    1e-8f
#define SEQ    2048
#define BATCH  2
#define NH     32
#define NKVH   8
#define HD     128
#define MROWS  (BATCH*SEQ)   // 4096
#define NQKV   6144          // 4096 q | 1024 k | 1024 v

typedef __attribute__((ext_vector_type(8))) short bf16x8;
typedef __attribute__((ext_vector_type(4))) short bf16x4;
typedef __attribute__((ext_vector_type(4))) float f32x4;

__device__ __forceinline__ void gload_lds16(const void* g, void* lds) {
  __builtin_amdgcn_global_load_lds((__attribute__((address_space(1))) void*)g,
                                   (__attribute__((address_space(3))) void*)lds,
                                   16, 0, 0);
}

__device__ __forceinline__ unsigned short f2bf(float f) {
  __hip_bfloat16 h = __float2bfloat16(f);
  return *reinterpret_cast<unsigned short*>(&h);
}

__device__ __forceinline__ void store_c(float* p, float v) { *p = v; }
__device__ __forceinline__ void store_c(__hip_bfloat16* p, float v) { *p = __float2bfloat16(v); }

__device__ __forceinline__ bf16x8 lds_read8_b64(const short* p) {
  bf16x4 lo = *(const bf16x4*)p;
  bf16x4 hi = *(const bf16x4*)(p + 4);
  bf16x8 r;
  r[0]=lo[0]; r[1]=lo[1]; r[2]=lo[2]; r[3]=lo[3];
  r[4]=hi[0]; r[5]=hi[1]; r[6]=hi[2]; r[7]=hi[3];
  return r;
}

// ---------------- DoRA W_d row (device helper) ----------------
__device__ __forceinline__ void wd_row(const float* __restrict__ W, const float* __restrict__ A,
                                       const float* __restrict__ B, const float* __restrict__ m,
                                       unsigned short* __restrict__ out, int row, int tid,
                                       float* wsum) {
  float bl[RANK];
#pragma unroll
  for (int t = 0; t < RANK; ++t) bl[t] = SCALING * B[row*RANK + t];
  float ev[16];
  float ss = 0.f;
#pragma unroll
  for (int it = 0; it < 4; ++it) {
    const int j = it*1024 + tid*4;
    const float4 wv = *(const float4*)&W[(size_t)row*HIDDEN + j];
    float e0 = wv.x, e1 = wv.y, e2 = wv.z, e3 = wv.w;
#pragma unroll
    for (int t = 0; t < RANK; ++t) {
      const float4 av = *(const float4*)&A[t*HIDDEN + j];
      e0 += bl[t]*av.x; e1 += bl[t]*av.y; e2 += bl[t]*av.z; e3 += bl[t]*av.w;
    }
    ev[it*4+0]=e0; ev[it*4+1]=e1; ev[it*4+2]=e2; ev[it*4+3]=e3;
    ss += e0*e0 + e1*e1 + e2*e2 + e3*e3;
  }
#pragma unroll
  for (int off = 32; off > 0; off >>= 1) ss += __shfl_down(ss, off, 64);
  if ((tid & 63) == 0) wsum[tid >> 6] = ss;
  __syncthreads();
  const float norm = sqrtf(wsum[0]+wsum[1]+wsum[2]+wsum[3]);
  const float scl = m[row] / (norm + EPS);
#pragma unroll
  for (int it = 0; it < 4; ++it) {
    const int j = it*1024 + tid*4;
    ushort4 pk;
    pk.x = f2bf(ev[it*4+0]*scl); pk.y = f2bf(ev[it*4+1]*scl);
    pk.z = f2bf(ev[it*4+2]*scl); pk.w = f2bf(ev[it*4+3]*scl);
    *(ushort4*)&out[(size_t)row*HIDDEN + j] = pk;
  }
}

// ---------------- prep: cast x -> bf16 + all DoRA W_d in one launch ----------------
__launch_bounds__(256)
__global__ void prep_kernel(const float* __restrict__ x, unsigned short* __restrict__ xbf,
                            const float* Wq, const float* Aq, const float* Bq, const float* mq, unsigned short* wdq,
                            const float* Wk, const float* Ak, const float* Bk, const float* mk, unsigned short* wdk,
                            const float* Wv, const float* Av, const float* Bv, const float* mv, unsigned short* wdv,
                            const float* Wo, const float* Ao, const float* Bo, const float* mo, unsigned short* wdo) {
  __shared__ float wsum[4];
  const int bid = blockIdx.x;
  const int tid = threadIdx.x;
  if (bid < 16384) {
    const size_t i = ((size_t)bid * 256 + tid) * 4;
    const float4 v = *(const float4*)&x[i];
    ushort4 pk;
    pk.x = f2bf(v.x); pk.y = f2bf(v.y); pk.z = f2bf(v.z); pk.w = f2bf(v.w);
    *(ushort4*)&xbf[i] = pk;
  } else if (bid < 20480) {
    wd_row(Wq, Aq, Bq, mq, wdq, bid - 16384, tid, wsum);
  } else if (bid < 21504) {
    wd_row(Wk, Ak, Bk, mk, wdk, bid - 20480, tid, wsum);
  } else if (bid < 22528) {
    wd_row(Wv, Av, Bv, mv, wdv, bid - 21504, tid, wsum);
  } else {
    wd_row(Wo, Ao, Bo, mo, wdo, bid - 22528, tid, wsum);
  }
}

__launch_bounds__(256)
__global__ void wd_kernel(const float* __restrict__ W, const float* __restrict__ A,
                          const float* __restrict__ B, const float* __restrict__ m,
                          unsigned short* __restrict__ out) {
  __shared__ float wsum[4];
  wd_row(W, A, B, m, out, blockIdx.x, threadIdx.x, wsum);
}

// ---------------- 256-row pipelined bf16 GEMM: C[M,N] = A[M,K] * B[N,K]^T ----------------
// ROUND-3 VERBATIM (verified passing, QKV 228us). Tile = 256 x (NREP*64); NREP=3 QKV
// (grid 512 = 2 rounds), NREP=4 O-proj (grid 256). ONE barrier per phase; fragment
// ds_reads software-pipelined one phase ahead into double-buffered regs. Section p =
// [MFMA p][reads p+1][issue unit p+6][vmcnt(6) if p even][BAR]. RAW: vmcnt(6) =>
// units <= s+3 landed before section s+1 reads. WAR: rewrite unit issues >=1 barrier
// after the region's lgkm-drained last read.
__device__ __forceinline__ void stage_u(const __hip_bfloat16* __restrict__ Ab,
                                        const __hip_bfloat16* __restrict__ Bb,
                                        const int K, __hip_bfloat16* sbuf,
                                        const int par, const int tau, const int j,
                                        const int w, const int l, const int kchunk) {
  const __hip_bfloat16* src = (j & 1) ? Bb : Ab;
  __hip_bfloat16* dst = sbuf + (par << 15) + (j << 13);
  const int k0 = (tau << 6) + ((j >> 1) << 5) + (kchunk << 3);
  const int r0 = (w << 4) + (l >> 2);
  gload_lds16(src + (size_t)r0 * K + k0, dst + (w << 9));
  gload_lds16(src + (size_t)(r0 + 128) * K + k0, dst + 4096 + (w << 9));
}

template<typename CT, int NREP>
__launch_bounds__(512, 2)
__global__ void gemm256(const __hip_bfloat16* __restrict__ A,
                        const __hip_bfloat16* __restrict__ B,
                        CT* __restrict__ C, const int M, const int N, const int K) {
  (void)M;
  __shared__ __hip_bfloat16 sb[65536];
  const int tid = threadIdx.x;
  const int w = tid >> 6, l = tid & 63;
  const int wr = w >> 2, wc = w & 3;           // 2x4 wave grid; wave tile 128 x NREP*16
  const int q4 = l >> 4, ln = l & 15;
  const int nbn = N / (NREP * 64);
  const int cpx = gridDim.x >> 3;              // grid % 8 == 0 at both call sites
  const int fid = (blockIdx.x & 7) * cpx + (blockIdx.x >> 3);
  const int tM = (fid / nbn) << 8;
  const int tN = (fid % nbn) * (NREP * 64);
  const int NT = K >> 6;                       // 64, even
  const __hip_bfloat16* Ab = A + (size_t)tM * K;
  const __hip_bfloat16* Bb = B + (size_t)tN * K;
  // write-side pre-swizzle: thread covers slot (row=tid>>2, c=tid&3); f(row)=(tid>>3)&3
  const int kchunk = (l & 3) ^ ((l >> 3) & 3);
  // read-side: frag rows == ln (mod 16) -> f(row)=(ln>>1)&3, per-lane constant
  const int slotoff = (q4 ^ ((ln >> 1) & 3)) << 3;

  f32x4 acc[8][NREP] = {};
  bf16x8 af[2][4];
  bf16x8 bfr[2][NREP];
  const short* sp = (const short*)sb;
  const int arow0 = wr * 128 + ln;
  const int brow0 = wc * (NREP * 16) + ln;

  // prologue: units 0..5 = (0,U0..U3),(1,U0),(1,U1); [vmcnt(8)][BAR] => units 0,1 landed
#pragma unroll
  for (int s = 0; s < 6; ++s)
    stage_u(Ab, Bb, K, sb, (s >> 2) & 1, s >> 2, s & 3, w, l, kchunk);
  asm volatile("s_waitcnt vmcnt(8)" ::: "memory");
  __builtin_amdgcn_s_barrier();
#pragma unroll
  for (int i = 0; i < 4; ++i)
    af[0][i] = *(const bf16x8*)&sp[(arow0 + i*16) * 32 + slotoff];
#pragma unroll
  for (int i = 0; i < NREP; ++i)
    bfr[0][i] = *(const bf16x8*)&sp[8192 + (brow0 + i*16) * 32 + slotoff];

  for (int tt = 0; tt < NT; tt += 2) {
#pragma unroll
    for (int pp = 0; pp < 8; ++pp) {           // 2 K-tiles; all LDS bases compile-time
      const int q = pp & 3, ks = q >> 1, mh = q & 1;
      // ---- MFMA phase: regs loaded one section ago ----
      __builtin_amdgcn_s_setprio(1);
#pragma unroll
      for (int i = 0; i < 4; ++i)
#pragma unroll
        for (int ni = 0; ni < NREP; ++ni)
          acc[mh*4 + i][ni] = __builtin_amdgcn_mfma_f32_16x16x32_bf16(af[pp & 1][i], bfr[ks][ni], acc[mh*4+i][ni], 0, 0, 0);
      __builtin_amdgcn_s_setprio(0);
      // ---- ds_reads for phase pp+1 (issue during MFMA pipe drain) ----
      {
        const int pn = pp + 1;                 // pn==8 -> slot 0 of tile tt+2 (parity 0)
        const int nb  = ((pn >> 2) & 1) << 15;
        const int nks = (pn & 3) >> 1;
        const int nmh = pn & 1;
#pragma unroll
        for (int i = 0; i < 4; ++i)
          af[pn & 1][i] = *(const bf16x8*)&sp[nb + (nks << 14) + (arow0 + (nmh*4+i)*16) * 32 + slotoff];
        if ((pn & 1) == 0) {
#pragma unroll
          for (int i = 0; i < NREP; ++i)
            bfr[nks][i] = *(const bf16x8*)&sp[nb + 8192 + (nks << 14) + (brow0 + i*16) * 32 + slotoff];
        }
      }
      // ---- stage one unit (unit index = section + 6) ----
      {
        const int su = pp + 6;
        const int stau = tt + (su >> 2);
        if (stau < NT)
          stage_u(Ab, Bb, K, sb, (su >> 2) & 1, stau, su & 3, w, l, kchunk);
      }
      // ---- counted wait guarding next section's new-region reads ----
      if ((pp & 1) == 0)
        asm volatile("s_waitcnt vmcnt(6)" ::: "memory");
      __builtin_amdgcn_s_barrier();
    }
  }

  const int r0 = tM + wr * 128 + q4 * 4;
  const int c0 = tN + wc * (NREP * 16) + ln;
#pragma unroll
  for (int mi = 0; mi < 8; ++mi)
#pragma unroll
    for (int ni = 0; ni < NREP; ++ni)
#pragma unroll
      for (int r = 0; r < 4; ++r)
        store_c(&C[(size_t)(r0 + mi * 16 + r) * N + c0 + ni * 16], acc[mi][ni][r]);
}

// ---------------- flash attention v2 (causal, GQA) ----------------
// Round 6 change (T14 async-STAGE on V only): V tile held in 4x uint4 regs across
// iterations; loads for iteration j+1 issue AFTER softmax(j) (s[] regs dead there),
// hiding HBM latency under the PV section. Vt LDS writes stay between BAR1 and BAR2
// -> LDS hazard schedule identical to the verified version.
#define VT_S 68
#define PS_S 68
__launch_bounds__(256, 3)
__global__ void attn_kernel(const __hip_bfloat16* __restrict__ qkv,
                            __hip_bfloat16* __restrict__ out) {
  const int bid = blockIdx.x;
  const int qt = 15 - (bid >> 6);      // big tiles first
  const int hb = bid & 63;
  const int h  = hb & 31;
  const int b  = hb >> 5;
  const int kvh = h >> 2;
  const int tid = threadIdx.x;
  const int w = tid >> 6, l = tid & 63;
  const int q4 = l >> 4;
  const int ln = l & 15;
  const int sw = ln & 7;

  __shared__ __hip_bfloat16 Ks[64*128];
  __shared__ __hip_bfloat16 Vt[128*VT_S];
  __shared__ __hip_bfloat16 Ps[4][2][16*PS_S];

  const __hip_bfloat16* kb = qkv + (size_t)(b*SEQ)*NQKV + HIDDEN + kvh*HD;
  const __hip_bfloat16* vb = qkv + (size_t)(b*SEQ)*NQKV + (HIDDEN+1024) + kvh*HD;

  const int Q0 = qt*128;

  const int krow = l >> 4;
  const int kchunk = ((l & 15) ^ krow ^ ((w & 1) << 2)) * 8;

  const int vc4 = (tid & 15) * 4;
  const int vd0 = (tid >> 4) * 8;

  bf16x8 aq[2][4];
#pragma unroll
  for (int hf = 0; hf < 2; ++hf) {
    const __hip_bfloat16* qr = qkv + (size_t)(b*SEQ + Q0 + hf*64 + w*16 + ln)*NQKV + h*HD;
#pragma unroll
    for (int ks = 0; ks < 4; ++ks) {
      uint4 raw = *(const uint4*)(qr + ks*32 + q4*8);
      aq[hf][ks] = *(const bf16x8*)&raw;
    }
  }

  f32x4 o[2][8] = {};
  float mx[2] = {-1e30f, -1e30f};
  float lsum[2] = {0.f, 0.f};
  const float sc = 0.08838834764831845f;  // 1/sqrt(128)
  const int qabs0 = Q0 + w*16 + ln;

  const int jmax = 2*qt + 1;

  // preload V regs for j = 0
  uint4 vr0, vr1, vr2, vr3;
  {
    const __hip_bfloat16* vp = vb + (size_t)(vc4)*NQKV + vd0;
    vr0 = *(const uint4*)(vp + 0*NQKV);
    vr1 = *(const uint4*)(vp + 1*NQKV);
    vr2 = *(const uint4*)(vp + 2*NQKV);
    vr3 = *(const uint4*)(vp + 3*NQKV);
  }

  for (int j = 0; j <= jmax; ++j) {
    const int do0 = (j <= 2*qt);
    __syncthreads();
    // stage K (64x128), swizzled DMA
#pragma unroll
    for (int i = 0; i < 4; ++i) {
      const int rr = i*16 + w*4;
      gload_lds16(kb + (size_t)(j*64 + rr + krow)*NQKV + kchunk, &Ks[rr*128]);
    }
    // write V regs (loaded one iteration ago) transposed -> Vt
    {
      const unsigned short* p0 = (const unsigned short*)&vr0;
      const unsigned short* p1 = (const unsigned short*)&vr1;
      const unsigned short* p2 = (const unsigned short*)&vr2;
      const unsigned short* p3 = (const unsigned short*)&vr3;
#pragma unroll
      for (int t = 0; t < 8; ++t) {
        ushort4 pk; pk.x = p0[t]; pk.y = p1[t]; pk.z = p2[t]; pk.w = p3[t];
        *(ushort4*)&Vt[(vd0 + t)*VT_S + vc4] = pk;
      }
    }
    __syncthreads();

    // S^T = K Q^T : s[hf][nt] C-layout -> kv = nt*16+q4*4+r, q = ln
    f32x4 s[2][4] = {};
    const short* Kp = (const short*)Ks;
#pragma unroll
    for (int ks = 0; ks < 4; ++ks) {
      const int slot = ((ks*4 + q4) ^ sw) * 8;
#pragma unroll
      for (int nt = 0; nt < 4; ++nt) {
        bf16x8 bk = *(const bf16x8*)&Kp[(nt*16 + ln)*128 + slot];
        if (do0) s[0][nt] = __builtin_amdgcn_mfma_f32_16x16x32_bf16(bk, aq[0][ks], s[0][nt], 0, 0, 0);
        s[1][nt] = __builtin_amdgcn_mfma_f32_16x16x32_bf16(bk, aq[1][ks], s[1][nt], 0, 0, 0);
      }
    }

    // softmax per half (lane owns q row = hf*64 + w*16 + ln)
#pragma unroll
    for (int hf = 0; hf < 2; ++hf) {
      if (hf == 0 && !do0) continue;
      const int qabs = qabs0 + hf*64;
      if (j == 2*qt + hf) {
#pragma unroll
        for (int nt = 0; nt < 4; ++nt)
#pragma unroll
          for (int r = 0; r < 4; ++r) {
            const int kvabs = j*64 + nt*16 + q4*4 + r;
            if (kvabs > qabs) s[hf][nt][r] = -1e30f;
          }
      }
      float vmax = mx[hf];
#pragma unroll
      for (int nt = 0; nt < 4; ++nt)
#pragma unroll
        for (int r = 0; r < 4; ++r) vmax = fmaxf(vmax, s[hf][nt][r]);
      vmax = fmaxf(vmax, __shfl_xor(vmax, 16, 64));
      vmax = fmaxf(vmax, __shfl_xor(vmax, 32, 64));
      const float alpha = __expf((mx[hf] - vmax) * sc);
      float rs = 0.f;
#pragma unroll
      for (int nt = 0; nt < 4; ++nt)
#pragma unroll
        for (int r = 0; r < 4; ++r) {
          const float e = __expf((s[hf][nt][r] - vmax) * sc);
          s[hf][nt][r] = e; rs += e;
        }
      rs += __shfl_xor(rs, 16, 64);
      rs += __shfl_xor(rs, 32, 64);
      mx[hf] = vmax;
      lsum[hf] = lsum[hf]*alpha + rs;
#pragma unroll
      for (int r = 0; r < 4; ++r) {
        const float ar = __shfl(alpha, q4*4 + r, 64);
#pragma unroll
        for (int ni = 0; ni < 8; ++ni) o[hf][ni][r] *= ar;
      }
      __hip_bfloat16* Pw = Ps[w][hf];
#pragma unroll
      for (int nt = 0; nt < 4; ++nt) {
        ushort4 pk;
        pk.x = f2bf(s[hf][nt][0]); pk.y = f2bf(s[hf][nt][1]);
        pk.z = f2bf(s[hf][nt][2]); pk.w = f2bf(s[hf][nt][3]);
        *(ushort4*)&Pw[ln*PS_S + nt*16 + q4*4] = pk;
      }
    }

    // issue V loads for next iteration (s[] regs dead here; latency hides under PV)
    {
      const int jn = (j < jmax) ? j + 1 : j;
      const __hip_bfloat16* vp = vb + (size_t)(jn*64 + vc4)*NQKV + vd0;
      vr0 = *(const uint4*)(vp + 0*NQKV);
      vr1 = *(const uint4*)(vp + 1*NQKV);
      vr2 = *(const uint4*)(vp + 2*NQKV);
      vr3 = *(const uint4*)(vp + 3*NQKV);
    }

    // O += P V (V-frags read once, applied to both halves)
    const short* Vp = (const short*)Vt;
    const short* Pp0 = (const short*)Ps[w][0];
    const short* Pp1 = (const short*)Ps[w][1];
#pragma unroll
    for (int ks = 0; ks < 2; ++ks) {
      bf16x8 ap0 = lds_read8_b64(&Pp0[ln*PS_S + ks*32 + q4*8]);
      bf16x8 ap1 = lds_read8_b64(&Pp1[ln*PS_S + ks*32 + q4*8]);
#pragma unroll
      for (int ni = 0; ni < 8; ++ni) {
        bf16x8 bv = lds_read8_b64(&Vp[(ni*16 + ln)*VT_S + ks*32 + q4*8]);
        if (do0) o[0][ni] = __builtin_amdgcn_mfma_f32_16x16x32_bf16(ap0, bv, o[0][ni], 0, 0, 0);
        o[1][ni] = __builtin_amdgcn_mfma_f32_16x16x32_bf16(ap1, bv, o[1][ni], 0, 0, 0);
      }
    }
  }

  // epilogue
#pragma unroll
  for (int hf = 0; hf < 2; ++hf) {
    const int row0 = b*SEQ + Q0 + hf*64 + w*16 + q4*4;
#pragma unroll
    for (int r = 0; r < 4; ++r) {
      const float lr = __shfl(lsum[hf], q4*4 + r, 64);
      const float inv = 1.f / lr;
#pragma unroll
      for (int ni = 0; ni < 8; ++ni)
        out[(size_t)(row0 + r)*HIDDEN + h*HD + ni*16 + ln] = __float2bfloat16(o[hf][ni][r] * inv);
    }
  }
}

extern "C" void kernel_launch(void* const* d_in, const int* in_sizes, int n_in,
                              void* d_out, int out_size, void* d_ws, size_t ws_size,
                              hipStream_t stream) {
  (void)in_sizes; (void)n_in; (void)out_size;
  const float* x  = (const float*)d_in[0];
  const float* Wq = (const float*)d_in[2];
  const float* Aq = (const float*)d_in[3];
  const float* Bq = (const float*)d_in[4];
  const float* mq = (const float*)d_in[5];
  const float* Wk = (const float*)d_in[6];
  const float* Ak = (const float*)d_in[7];
  const float* Bk = (const float*)d_in[8];
  const float* mk = (const float*)d_in[9];
  const float* Wv = (const float*)d_in[10];
  const float* Av = (const float*)d_in[11];
  const float* Bv = (const float*)d_in[12];
  const float* mv = (const float*)d_in[13];
  const float* Wo = (const float*)d_in[14];
  const float* Ao = (const float*)d_in[15];
  const float* Bo = (const float*)d_in[16];
  const float* mo = (const float*)d_in[17];

  char* ws = (char*)d_ws;
  __hip_bfloat16* xbf = (__hip_bfloat16*)ws;                          // 32 MiB, reused as attn_out
  __hip_bfloat16* wd  = (__hip_bfloat16*)(ws + (size_t)33554432);     // 48 MiB
  __hip_bfloat16* qkv = (__hip_bfloat16*)(ws + (size_t)83886080);     // 48 MiB
  const bool big = ws_size >= (size_t)167772160;                      // 160 MiB
  __hip_bfloat16* wdo = big ? (__hip_bfloat16*)(ws + (size_t)134217728) : wd;

  prep_kernel<<<big ? 26624 : 22528, 256, 0, stream>>>(
      x, (unsigned short*)xbf,
      Wq, Aq, Bq, mq, (unsigned short*)wd,
      Wk, Ak, Bk, mk, (unsigned short*)(wd + (size_t)4096*4096),
      Wv, Av, Bv, mv, (unsigned short*)(wd + (size_t)5120*4096),
      Wo, Ao, Bo, mo, (unsigned short*)wdo);
  gemm256<__hip_bfloat16, 3><<<512, 512, 0, stream>>>(xbf, wd, qkv, MROWS, NQKV, HIDDEN);
  if (!big)
    wd_kernel<<<4096, 256, 0, stream>>>(Wo, Ao, Bo, mo, (unsigned short*)wdo);
  attn_kernel<<<1024, 256, 0, stream>>>(qkv, xbf);
  gemm256<float, 4><<<256, 512, 0, stream>>>(xbf, wdo, (float*)d_out, MROWS, HIDDEN, HIDDEN);
}